// Round 11
// baseline (683.468 us; speedup 1.0000x reference)
//
#include <hip/hip_runtime.h>
#include <hip/hip_bf16.h>
#include <math.h>

#define TT 365
#define BT 23360
#define NBLK 256

typedef __hip_bfloat16 bf16;
typedef __attribute__((ext_vector_type(8))) short s16x8;
typedef __attribute__((ext_vector_type(4))) float f32x4;

__device__ __forceinline__ float b2f(bf16 v) { return __bfloat162float(v); }
__device__ __forceinline__ bf16  f2b(float v) { return __float2bfloat16(v); }
__device__ __forceinline__ float u2f(unsigned u) { return __uint_as_float(u); }
__device__ __forceinline__ short f2bs(float v) { bf16 h = __float2bfloat16(v); return *reinterpret_cast<short*>(&h); }
__device__ __forceinline__ void unpack8(uint4 raw, float* v) {
    v[0] = u2f(raw.x << 16); v[1] = u2f(raw.x & 0xffff0000u);
    v[2] = u2f(raw.y << 16); v[3] = u2f(raw.y & 0xffff0000u);
    v[4] = u2f(raw.z << 16); v[5] = u2f(raw.z & 0xffff0000u);
    v[6] = u2f(raw.w << 16); v[7] = u2f(raw.w & 0xffff0000u);
}

// ---- software grid barrier: counter slot per barrier, zeroed before launch ----
__device__ __forceinline__ void gridbar(unsigned* __restrict__ ctr, int slot) {
    __syncthreads();
    if (threadIdx.x == 0) {
        __threadfence();                      // release: my writes visible device-wide
        atomicAdd(&ctr[slot], 1u);            // device-scope RMW
        while (__hip_atomic_load(&ctr[slot], __ATOMIC_ACQUIRE, __HIP_MEMORY_SCOPE_AGENT)
               < (unsigned)NBLK) {
            __builtin_amdgcn_s_sleep(2);
        }
        __threadfence();                      // acquire: others' writes visible to me
    }
    __syncthreads();
}

struct Params {
    const float *x; const int *pos;
    const float *w1, *b1, *g1, *e1;
    const float *w2, *b2, *g2, *e2;
    const float *w3, *b3, *g3, *e3;
    const float *ws1, *ws2;
    const float *wi, *bi, *gi, *ei;
    const float *wk, *bk, *wq, *bq;
    const float *wm, *bm, *gm, *em;
    const float *wd1, *bd1, *gd1, *ed1;
    const float *wd2, *bd2, *gd2, *ed2;
    const float *wc, *bc;
    float *out;
    bf16 *actA, *actB, *whi, *wlo;
    float *tab, *partsA, *partsB, *pooled, *sebuf, *esum, *yvb;
    float *pre1, *pre2, *pre3;
    unsigned *bar;
};

struct SmemL1 { float As[64][17]; float Ws[16][65]; float red_s[4][64]; float red_q[4][64]; };
struct SmemMF { s16x8 Wl[2][16][64]; float red_s[4][64]; float red_q[4][64]; float scb[256]; float shb[256]; };
struct SmemPool { float scb[256], shb[256]; float pp[8][256]; };
struct SmemSe { float pl[256]; float hidden[16]; };
struct SmemAttn { float aw[4][368]; };

__device__ __forceinline__ void compute_coef(const float* __restrict__ parts,
                                             const float* __restrict__ g,
                                             const float* __restrict__ beta,
                                             int Ncols, float* scb, float* shb, int t) {
    if (t < Ncols) {
        float s = 0.f, q = 0.f;
        const float* ps = parts + t;
        const float* pq = parts + 256 + t;
        for (int r = 0; r < 365; ++r) { s += ps[r * 512]; q += pq[r * 512]; }
        float mu = s * (1.f / (float)BT);
        float var = q * (1.f / (float)BT) - mu * mu;
        float sc = rsqrtf(var + 1e-5f) * g[t];
        scb[t] = sc; shb[t] = beta[t] - mu * sc;
    }
}

__device__ void l1_tile(int bx, const Params& p, SmemL1& sm, int t) {
    const int tx = t & 15, ty = t >> 4;
    const int row0 = bx * 64;
    float acc[4][4];
#pragma unroll
    for (int rr = 0; rr < 4; ++rr)
#pragma unroll
        for (int cc = 0; cc < 4; ++cc) acc[rr][cc] = 0.f;
#pragma unroll
    for (int i = 0; i < 4; ++i) {
        int idx = t + i * 256, r = idx >> 4, c = idx & 15;
        sm.As[r][c] = (c < 10) ? p.x[(size_t)(row0 + r) * 10 + c] : 0.f;
    }
#pragma unroll
    for (int i = 0; i < 4; ++i) {
        int idx = t + i * 256, c = idx >> 4, kk = idx & 15;
        sm.Ws[kk][c] = (kk < 10) ? p.w1[(size_t)c * 10 + kk] : 0.f;
    }
    __syncthreads();
#pragma unroll
    for (int kk = 0; kk < 10; ++kk) {
        float a[4];
#pragma unroll
        for (int rr = 0; rr < 4; ++rr) a[rr] = sm.As[ty * 4 + rr][kk];
#pragma unroll
        for (int cc = 0; cc < 4; ++cc) {
            float w = sm.Ws[kk][cc * 16 + tx];
#pragma unroll
            for (int rr = 0; rr < 4; ++rr) acc[rr][cc] = fmaf(a[rr], w, acc[rr][cc]);
        }
    }
    float s_cc[4], q_cc[4];
#pragma unroll
    for (int cc = 0; cc < 4; ++cc) { s_cc[cc] = 0.f; q_cc[cc] = 0.f; }
#pragma unroll
    for (int rr = 0; rr < 4; ++rr) {
        int row = row0 + ty * 4 + rr;
#pragma unroll
        for (int cc = 0; cc < 4; ++cc) {
            int col = cc * 16 + tx;
            float v = acc[rr][cc] + p.b1[col];
            p.actB[(size_t)row * 64 + col] = f2b(v);
            s_cc[cc] += v; q_cc[cc] += v * v;
        }
    }
    int w = t >> 6;
#pragma unroll
    for (int cc = 0; cc < 4; ++cc) {
        float s = s_cc[cc], q = q_cc[cc];
        s += __shfl_xor(s, 16); q += __shfl_xor(q, 16);
        s += __shfl_xor(s, 32); q += __shfl_xor(q, 32);
        if ((t & 63) < 16) { sm.red_s[w][cc * 16 + tx] = s; sm.red_q[w][cc * 16 + tx] = q; }
    }
    __syncthreads();
    if (t < 64) {
        float* pr = p.partsA + (size_t)bx * 512;
        pr[t]       = sm.red_s[0][t] + sm.red_s[1][t] + sm.red_s[2][t] + sm.red_s[3][t];
        pr[256 + t] = sm.red_q[0][t] + sm.red_q[1][t] + sm.red_q[2][t] + sm.red_q[3][t];
    }
}

template<int MODE, int K>
__device__ void mfma_tile(int bx, int by, const bf16* __restrict__ A,
                          const bf16* __restrict__ Whi, const bf16* __restrict__ Wlo,
                          const float* __restrict__ bias, bf16* __restrict__ Y, int ldY,
                          float* __restrict__ partials, const float* __restrict__ sebuf,
                          SmemMF& sm, int t) {
    constexpr int KC = (K > 128) ? 128 : K;
    const int wave = t >> 6, lane = t & 63;
    const int n16 = lane & 15, quad = lane >> 4;
    const int m0 = bx * 64 + wave * 16;
    const int col0 = by * 64;
    const int sc_ = t & 63, skg0 = t >> 6;
    const bf16* gh = Whi + (size_t)(col0 + sc_) * K;
    const bf16* gl = Wlo + (size_t)(col0 + sc_) * K;
    __syncthreads();
#pragma unroll
    for (int kg = skg0; kg < KC / 8; kg += 4) {
        sm.Wl[0][kg][sc_] = *(const s16x8*)(gh + kg * 8);
        sm.Wl[1][kg][sc_] = *(const s16x8*)(gl + kg * 8);
    }
    __syncthreads();
    const int arow = m0 + n16;
    const float* sev = (MODE == 2) ? (sebuf + (arow / TT) * 256) : nullptr;
    const bf16* Ap = A + (size_t)arow * K + quad * 8;
    s16x8 af[K / 32];
#pragma unroll
    for (int i = 0; i < K / 32; ++i) {
        s16x8 raw = *(const s16x8*)(Ap + i * 32);
        if (MODE) {
            int kb = i * 32 + quad * 8;
#pragma unroll
            for (int j = 0; j < 8; ++j) {
                float y = u2f(((unsigned)(unsigned short)raw[j]) << 16);
                float v = fmaxf(fmaf(y, sm.scb[kb + j], sm.shb[kb + j]), 0.f);
                if (MODE == 2) v += sev[kb + j];
                raw[j] = f2bs(v);
            }
        }
        af[i] = raw;
    }
    f32x4 acc[4];
    f32x4 zero = {0.f, 0.f, 0.f, 0.f};
#pragma unroll
    for (int ct = 0; ct < 4; ++ct) acc[ct] = zero;
#pragma unroll
    for (int kc = 0; kc < K; kc += KC) {
        if (kc) {
            __syncthreads();
#pragma unroll
            for (int kg = skg0; kg < KC / 8; kg += 4) {
                sm.Wl[0][kg][sc_] = *(const s16x8*)(gh + kc + kg * 8);
                sm.Wl[1][kg][sc_] = *(const s16x8*)(gl + kc + kg * 8);
            }
            __syncthreads();
        }
#pragma unroll
        for (int i = 0; i < KC / 32; ++i) {
            const int kgq = i * 4 + quad;
            const s16x8 a = af[(kc >> 5) + i];
#pragma unroll
            for (int ct = 0; ct < 4; ++ct) {
                s16x8 bl = sm.Wl[1][kgq][ct * 16 + n16];
                s16x8 bh = sm.Wl[0][kgq][ct * 16 + n16];
                acc[ct] = __builtin_amdgcn_mfma_f32_16x16x32_bf16(a, bl, acc[ct], 0, 0, 0);
                acc[ct] = __builtin_amdgcn_mfma_f32_16x16x32_bf16(a, bh, acc[ct], 0, 0, 0);
            }
        }
    }
#pragma unroll
    for (int ct = 0; ct < 4; ++ct) {
        int col = col0 + ct * 16 + n16;
        float bv = bias[col];
        float s = 0.f, q = 0.f;
#pragma unroll
        for (int r = 0; r < 4; ++r) {
            float v = acc[ct][r] + bv;
            int row = m0 + quad * 4 + r;
            Y[(size_t)row * ldY + col] = f2b(v);
            s += v; q += v * v;
        }
        s += __shfl_xor(s, 16); q += __shfl_xor(q, 16);
        s += __shfl_xor(s, 32); q += __shfl_xor(q, 32);
        if (quad == 0) { sm.red_s[wave][ct * 16 + n16] = s; sm.red_q[wave][ct * 16 + n16] = q; }
    }
    if (partials) {
        __syncthreads();
        if (t < 64) {
            float* pr = partials + (size_t)bx * 512;
            pr[col0 + t]       = sm.red_s[0][t] + sm.red_s[1][t] + sm.red_s[2][t] + sm.red_s[3][t];
            pr[256 + col0 + t] = sm.red_q[0][t] + sm.red_q[1][t] + sm.red_q[2][t] + sm.red_q[3][t];
        }
    }
}

__device__ void pool_tile(int b, int part, const Params& p, SmemPool& sm, int t) {
    const int cg_ = t & 31, rs = t >> 5;
    float acc[8] = {0.f,0.f,0.f,0.f,0.f,0.f,0.f,0.f};
    const int r0 = part * 46;
#pragma unroll
    for (int i = 0; i < 6; ++i) {
        int l = rs + i * 8, r = r0 + l;
        if (l < 46 && r < TT) {
            uint4 raw = *(const uint4*)(p.actB + ((size_t)b * TT + r) * 256 + cg_ * 8);
            float v[8];
            unpack8(raw, v);
#pragma unroll
            for (int j = 0; j < 8; ++j)
                acc[j] += fmaxf(fmaf(v[j], sm.scb[cg_ * 8 + j], sm.shb[cg_ * 8 + j]), 0.f);
        }
    }
#pragma unroll
    for (int j = 0; j < 8; ++j) sm.pp[rs][cg_ * 8 + j] = acc[j];
    __syncthreads();
    float s = 0.f;
#pragma unroll
    for (int r = 0; r < 8; ++r) s += sm.pp[r][t];
    atomicAdd(&p.pooled[b * 256 + t], s);
    __syncthreads();
}

__device__ void esum_tile(int b, int part, const Params& p, SmemPool& sm, int t) {
    const int cg_ = t & 31, rs = t >> 5;
    float acc[8] = {0.f,0.f,0.f,0.f,0.f,0.f,0.f,0.f};
    const int r0 = part * 46;
#pragma unroll
    for (int i = 0; i < 6; ++i) {
        int l = rs + i * 8, r = r0 + l;
        if (l < 46 && r < TT) {
            uint4 raw = *(const uint4*)(p.actB + ((size_t)b * TT + r) * 256 + cg_ * 8);
            float v[8];
            unpack8(raw, v);
#pragma unroll
            for (int j = 0; j < 8; ++j) acc[j] += v[j];
        }
    }
    __syncthreads();
#pragma unroll
    for (int j = 0; j < 8; ++j) sm.pp[rs][cg_ * 8 + j] = acc[j];
    __syncthreads();
    float s = 0.f;
#pragma unroll
    for (int r = 0; r < 8; ++r) s += sm.pp[r][t];
    atomicAdd(&p.esum[b * 256 + t], s);
    __syncthreads();
}

// ---- tiny pre-kernel: zero barrier counters + pooled/esum ----
__global__ __launch_bounds__(256) void zerobar_kernel(unsigned* __restrict__ bar,
                                                      float* __restrict__ pooled,
                                                      float* __restrict__ esum) {
    int i = blockIdx.x * 256 + threadIdx.x;
    if (i < 32) bar[i] = 0u;
    if (i < 16384) { pooled[i] = 0.f; esum[i] = 0.f; }
}

// ================================ MEGA KERNEL ================================
__global__ __launch_bounds__(256) void mega_kernel(Params p) {
    __shared__ __align__(16) char smem_raw[36864];
    const int g = blockIdx.x, t = threadIdx.x;
    unsigned* bar = p.bar;

    // ---- S0: prep (weight split-cast, pos table) ----
    for (int i = g * 256 + t; i < 248064; i += 65536) {
        int i2 = i;
        if (i2 < 139264) {
            float w;
            if      (i2 < 8192)   w = p.w2[i2];
            else if (i2 < 40960)  w = p.w3[i2 - 8192];
            else if (i2 < 106496) w = p.wi[i2 - 40960];
            else                  w = p.wq[i2 - 106496];
            bf16 h = f2b(w);
            p.whi[i2] = h;
            p.wlo[i2] = f2b(w - b2f(h));
            continue;
        } i2 -= 139264;
        int c = i2 & 255, pp = i2 >> 8;
        float e = (float)(2 * (c >> 1)) * (1.f / 256.f);
        float ang = (float)pp * exp2f(-e * 9.96578428466209f);
        p.tab[i2] = (c & 1) ? cosf(ang) : sinf(ang);
    }
    gridbar(bar, 0);

    // ---- S1: L1 gemm -> actB, partsA ----
    {
        SmemL1& sm = *(SmemL1*)smem_raw;
        for (int tile = g; tile < 365; tile += NBLK) { __syncthreads(); l1_tile(tile, p, sm, t); }
    }
    gridbar(bar, 1);

    // ---- S2: L2 (K=64, MODE1, coef from partsA) -> actA, partsB ----
    {
        SmemMF& sm = *(SmemMF*)smem_raw;
        compute_coef(p.partsA, p.g1, p.e1, 64, sm.scb, sm.shb, t);
        for (int tile = g; tile < 730; tile += NBLK)
            mfma_tile<1, 64>(tile >> 1, tile & 1, p.actB, p.whi, p.wlo, p.b2,
                             p.actA, 128, p.partsB, nullptr, sm, t);
    }
    gridbar(bar, 2);

    // ---- S3: L3 (K=128, MODE1, coef from partsB) -> actB, partsA ----
    {
        SmemMF& sm = *(SmemMF*)smem_raw;
        compute_coef(p.partsB, p.g2, p.e2, 128, sm.scb, sm.shb, t);
        for (int tile = g; tile < 1460; tile += NBLK)
            mfma_tile<1, 128>(tile >> 2, tile & 3, p.actA, p.whi + 8192, p.wlo + 8192, p.b3,
                              p.actB, 256, p.partsA, nullptr, sm, t);
    }
    gridbar(bar, 3);

    // ---- S4: pool (bn3 from partsA) ----
    {
        SmemPool& sm = *(SmemPool*)smem_raw;
        compute_coef(p.partsA, p.g3, p.e3, 256, sm.scb, sm.shb, t);
        __syncthreads();
        for (int tile = g; tile < 512; tile += NBLK)
            pool_tile(tile >> 3, tile & 7, p, sm, t);
    }
    gridbar(bar, 4);

    // ---- S5: SE MLP (blocks 0..63) ----
    if (g < 64) {
        SmemSe& sm = *(SmemSe*)smem_raw;
        float pv = p.pooled[g * 256 + t] * (1.f / (float)TT);
        sm.pl[t] = pv;
        __syncthreads();
        if (t < 16) {
            float h = 0.f;
            for (int k2 = 0; k2 < 256; ++k2) h = fmaf(sm.pl[k2], p.ws1[t * 256 + k2], h);
            sm.hidden[t] = fmaxf(h, 0.f);
        }
        __syncthreads();
        float a = 0.f;
        for (int k2 = 0; k2 < 16; ++k2) a = fmaf(sm.hidden[k2], p.ws2[t * 16 + k2], a);
        a = 1.f / (1.f + expf(-a));
        p.sebuf[g * 256 + t] = a * pv;
    }
    gridbar(bar, 5);

    // ---- S6: inconv (K=256, MODE2) -> actA, partsB ----
    {
        SmemMF& sm = *(SmemMF*)smem_raw;
        compute_coef(p.partsA, p.g3, p.e3, 256, sm.scb, sm.shb, t);
        for (int tile = g; tile < 1460; tile += NBLK)
            mfma_tile<2, 256>(tile >> 2, tile & 3, p.actB, p.whi + 40960, p.wlo + 40960, p.bi,
                              p.actA, 256, p.partsB, p.sebuf, sm, t);
    }
    gridbar(bar, 6);

    // ---- S7: bn_i + relu + PE -> e = actB ----
    {
        SmemPool& sm = *(SmemPool*)smem_raw;
        compute_coef(p.partsB, p.gi, p.ei, 256, sm.scb, sm.shb, t);
        __syncthreads();
        for (int tile = g; tile < 2920; tile += NBLK) {
            int i = (tile * 256 + t) * 8;
            int col = i & 255, row = i >> 8;
            uint4 raw = *(const uint4*)(p.actA + i);
            float v[8];
            unpack8(raw, v);
            const float* tr = p.tab + p.pos[row] * 256 + col;
            bf16 tmp[8] __attribute__((aligned(16)));
#pragma unroll
            for (int j = 0; j < 8; ++j) {
                float o = fmaf(v[j], sm.scb[col + j], sm.shb[col + j]);
                tmp[j] = f2b(fmaxf(o, 0.f) + tr[j]);
            }
            *(uint4*)(p.actB + i) = *(const uint4*)tmp;
        }
    }
    gridbar(bar, 7);

    // ---- S8: esum (512 tiles) + q-proj (730 tiles) ----
    {
        for (int tile = g; tile < 1242; tile += NBLK) {
            if (tile < 512) {
                SmemPool& sm = *(SmemPool*)smem_raw;
                esum_tile(tile >> 3, tile & 7, p, sm, t);
            } else {
                SmemMF& sm = *(SmemMF*)smem_raw;
                int qp = tile - 512;
                mfma_tile<0, 256>(qp >> 1, qp & 1, p.actB, p.whi + 106496, p.wlo + 106496, p.bq,
                                  p.actA, 128, nullptr, nullptr, sm, t);
            }
        }
    }
    gridbar(bar, 8);

    // ---- S9: attention, wave = (b,h) ----
    {
        SmemAttn& sm = *(SmemAttn*)smem_raw;
        const int wv = t >> 6, lane = t & 63;
        const int bh = g * 4 + wv, b = bh >> 4, h = bh & 15;
        float* aw = sm.aw[wv];
        float4 es = *(const float4*)(p.esum + b * 256 + lane * 4);
        float ks[8];
#pragma unroll
        for (int d = 0; d < 8; ++d) {
            float4 wvv = *(const float4*)(p.wk + (size_t)(h * 8 + d) * 256 + lane * 4);
            ks[d] = es.x * wvv.x + es.y * wvv.y + es.z * wvv.z + es.w * wvv.w;
        }
#pragma unroll
        for (int off = 1; off < 64; off <<= 1)
#pragma unroll
            for (int d = 0; d < 8; ++d) ks[d] += __shfl_xor(ks[d], off);
#pragma unroll
        for (int d = 0; d < 8; ++d) ks[d] += (float)TT * p.bk[h * 8 + d];
        const float scale = 1.f / (sqrtf(8.f) * (float)TT);
        const bf16* qb = p.actA + (size_t)b * TT * 128 + h * 8;
        float sv[6];
        float m = -1e30f;
#pragma unroll
        for (int i = 0; i < 6; ++i) {
            int r = lane + i * 64;
            float s = -1e30f;
            if (r < TT) {
                uint4 raw = *(const uint4*)(qb + (size_t)r * 128);
                float v[8];
                unpack8(raw, v);
                float dot = 0.f;
#pragma unroll
                for (int j = 0; j < 8; ++j) dot = fmaf(v[j], ks[j], dot);
                s = dot * scale;
            }
            sv[i] = s;
            m = fmaxf(m, s);
        }
#pragma unroll
        for (int off = 1; off < 64; off <<= 1) m = fmaxf(m, __shfl_xor(m, off));
        float sum = 0.f;
#pragma unroll
        for (int i = 0; i < 6; ++i) {
            float ev = (sv[i] > -1e29f) ? expf(sv[i] - m) : 0.f;
            sv[i] = ev; sum += ev;
        }
#pragma unroll
        for (int off = 1; off < 64; off <<= 1) sum += __shfl_xor(sum, off);
        float inv = 1.f / sum;
#pragma unroll
        for (int i = 0; i < 6; ++i) {
            int r = lane + i * 64;
            if (r < TT) aw[r] = sv[i] * inv;
        }
        __syncthreads();
        const int half = lane & 1, rs = lane >> 1;
        float acc[8] = {0.f,0.f,0.f,0.f,0.f,0.f,0.f,0.f};
        const bf16* ebase = p.actB + (size_t)b * TT * 256 + h * 16 + half * 8;
#pragma unroll
        for (int i = 0; i < 12; ++i) {
            int r = rs + i * 32;
            if (r < TT) {
                uint4 raw = *(const uint4*)(ebase + (size_t)r * 256);
                float v[8];
                unpack8(raw, v);
                float a = aw[r];
#pragma unroll
                for (int j = 0; j < 8; ++j) acc[j] = fmaf(a, v[j], acc[j]);
            }
        }
#pragma unroll
        for (int off = 2; off < 64; off <<= 1)
#pragma unroll
            for (int j = 0; j < 8; ++j) acc[j] += __shfl_xor(acc[j], off);
        if (lane < 2) {
            float* op = p.yvb + b * 256 + h * 16 + half * 8;
#pragma unroll
            for (int j = 0; j < 8; ++j) op[j] = acc[j];
        }
    }
    gridbar(bar, 9);

    // ---- T1: tail L1 gemm (block = row): pre1 = yv @ wm^T + bm ----
    if (g < 64) {
        float* xrow = (float*)smem_raw;
        xrow[t] = p.yvb[g * 256 + t];
        __syncthreads();
        int col = t >> 1, half = t & 1;
        const float4* wr = (const float4*)(p.wm + (size_t)col * 256 + half * 128);
        const float4* xr = (const float4*)(xrow + half * 128);
        float s = 0.f;
#pragma unroll
        for (int j = 0; j < 32; ++j) {
            float4 w = wr[j], xv = xr[j];
            s += xv.x * w.x + xv.y * w.y + xv.z * w.z + xv.w * w.w;
        }
        s += __shfl_xor(s, 1);
        if (half == 0) p.pre1[g * 128 + col] = s + p.bm[col];
    }
    gridbar(bar, 10);

    // ---- T2: bn + tail L2 ----
    if (g < 64) {
        float* scb = (float*)smem_raw;
        float* shb = scb + 128;
        float* act = shb + 128;
        if (t < 128) {
            float s = 0.f, q = 0.f;
            for (int r = 0; r < 64; ++r) { float v = p.pre1[r * 128 + t]; s += v; q += v * v; }
            float mu = s * (1.f / 64.f), var = q * (1.f / 64.f) - mu * mu;
            float sc = rsqrtf(var + 1e-5f) * p.gm[t];
            scb[t] = sc; shb[t] = p.em[t] - mu * sc;
        }
        __syncthreads();
        if (t < 128) act[t] = fmaxf(fmaf(p.pre1[g * 128 + t], scb[t], shb[t]), 0.f);
        __syncthreads();
        int col = t >> 2, qtr = t & 3;
        const float4* wr = (const float4*)(p.wd1 + (size_t)col * 128 + qtr * 32);
        const float4* xr = (const float4*)(act + qtr * 32);
        float s = 0.f;
#pragma unroll
        for (int j = 0; j < 8; ++j) {
            float4 w = wr[j], xv = xr[j];
            s += xv.x * w.x + xv.y * w.y + xv.z * w.z + xv.w * w.w;
        }
        s += __shfl_xor(s, 1); s += __shfl_xor(s, 2);
        if (qtr == 0) p.pre2[g * 64 + col] = s + p.bd1[col];
    }
    gridbar(bar, 11);

    // ---- T3: bn + tail L3 ----
    if (g < 64) {
        float* scb = (float*)smem_raw;
        float* shb = scb + 128;
        float* act = shb + 128;
        if (t < 64) {
            float s = 0.f, q = 0.f;
            for (int r = 0; r < 64; ++r) { float v = p.pre2[r * 64 + t]; s += v; q += v * v; }
            float mu = s * (1.f / 64.f), var = q * (1.f / 64.f) - mu * mu;
            float sc = rsqrtf(var + 1e-5f) * p.gd1[t];
            scb[t] = sc; shb[t] = p.ed1[t] - mu * sc;
        }
        __syncthreads();
        if (t < 64) act[t] = fmaxf(fmaf(p.pre2[g * 64 + t], scb[t], shb[t]), 0.f);
        __syncthreads();
        int col = t >> 3, oct = t & 7;
        const float4* wr = (const float4*)(p.wd2 + (size_t)col * 64 + oct * 8);
        const float4* xr = (const float4*)(act + oct * 8);
        float s = 0.f;
#pragma unroll
        for (int j = 0; j < 2; ++j) {
            float4 w = wr[j], xv = xr[j];
            s += xv.x * w.x + xv.y * w.y + xv.z * w.z + xv.w * w.w;
        }
        s += __shfl_xor(s, 1); s += __shfl_xor(s, 2); s += __shfl_xor(s, 4);
        if (oct == 0) p.pre3[g * 32 + col] = s + p.bd2[col];
    }
    gridbar(bar, 12);

    // ---- T4: bn + classifier ----
    if (g < 64) {
        float* scb = (float*)smem_raw;
        float* shb = scb + 128;
        float* act = shb + 128;
        if (t < 32) {
            float s = 0.f, q = 0.f;
            for (int r = 0; r < 64; ++r) { float v = p.pre3[r * 32 + t]; s += v; q += v * v; }
            float mu = s * (1.f / 64.f), var = q * (1.f / 64.f) - mu * mu;
            float sc = rsqrtf(var + 1e-5f) * p.gd2[t];
            scb[t] = sc; shb[t] = p.ed2[t] - mu * sc;
        }
        __syncthreads();
        if (t < 32) act[t] = fmaxf(fmaf(p.pre3[g * 32 + t], scb[t], shb[t]), 0.f);
        __syncthreads();
        if (t < 10) {
            float s = p.bc[t];
            const float* wr = p.wc + t * 32;
#pragma unroll
            for (int j = 0; j < 32; ++j) s = fmaf(act[j], wr[j], s);
            p.out[g * 10 + t] = s;
        }
    }
}

// ---------------- launch ----------------

extern "C" void kernel_launch(void* const* d_in, const int* in_sizes, int n_in,
                              void* d_out, int out_size, void* d_ws, size_t ws_size,
                              hipStream_t stream) {
    (void)in_sizes; (void)n_in; (void)out_size; (void)ws_size;
    Params p;
    p.x  = (const float*)d_in[0];
    p.pos = (const int*)d_in[1];
    p.w1 = (const float*)d_in[2];  p.b1 = (const float*)d_in[3];
    p.g1 = (const float*)d_in[4];  p.e1 = (const float*)d_in[5];
    p.w2 = (const float*)d_in[6];  p.b2 = (const float*)d_in[7];
    p.g2 = (const float*)d_in[8];  p.e2 = (const float*)d_in[9];
    p.w3 = (const float*)d_in[10]; p.b3 = (const float*)d_in[11];
    p.g3 = (const float*)d_in[12]; p.e3 = (const float*)d_in[13];
    p.ws1 = (const float*)d_in[14]; p.ws2 = (const float*)d_in[15];
    p.wi = (const float*)d_in[16]; p.bi = (const float*)d_in[17];
    p.gi = (const float*)d_in[18]; p.ei = (const float*)d_in[19];
    p.wk = (const float*)d_in[20]; p.bk = (const float*)d_in[21];   // k before q!
    p.wq = (const float*)d_in[22]; p.bq = (const float*)d_in[23];
    p.wm = (const float*)d_in[24]; p.bm = (const float*)d_in[25];
    p.gm = (const float*)d_in[26]; p.em = (const float*)d_in[27];
    p.wd1 = (const float*)d_in[28]; p.bd1 = (const float*)d_in[29];
    p.gd1 = (const float*)d_in[30]; p.ed1 = (const float*)d_in[31];
    p.wd2 = (const float*)d_in[32]; p.bd2 = (const float*)d_in[33];
    p.gd2 = (const float*)d_in[34]; p.ed2 = (const float*)d_in[35];
    p.wc = (const float*)d_in[36]; p.bc = (const float*)d_in[37];
    p.out = (float*)d_out;

    char* w8 = (char*)d_ws;
    p.actA   = (bf16*)(w8);                    // 11,960,320
    p.actB   = (bf16*)(w8 + 11960320);         // 11,960,320
    p.whi    = (bf16*)(w8 + 23920640);         //    278,528
    p.wlo    = (bf16*)(w8 + 24199168);         //    278,528
    p.tab    = (float*)(w8 + 24477696);        //    435,200
    p.partsA = (float*)(w8 + 24912896);        //    747,520
    p.partsB = (float*)(w8 + 25660416);        //    747,520
    p.pooled = (float*)(w8 + 26407936);        //     65,536
    p.sebuf  = (float*)(w8 + 26473472);        //     65,536
    p.esum   = (float*)(w8 + 26539008);        //     65,536
    p.yvb    = (float*)(w8 + 26604544);        //     65,536
    p.pre1   = (float*)(w8 + 26670080);        //     32,768
    p.pre2   = (float*)(w8 + 26702848);        //     16,384
    p.pre3   = (float*)(w8 + 26719232);        //      8,192
    p.bar    = (unsigned*)(w8 + 26727424);     //        128

    zerobar_kernel<<<64, 256, 0, stream>>>(p.bar, p.pooled, p.esum);
    mega_kernel<<<NBLK, 256, 0, stream>>>(p);
}